// Round 2
// baseline (87.356 us; speedup 1.0000x reference)
//
#include <hip/hip_runtime.h>

// pred_masks:   [B=8, NP=8, 512, 512] f32 logits
// target_masks: [B=8, NT=16, 512, 512] f32 in [0,1]
// out: scalar f32 = 5 * mean_{b,i} min_j [ mean(softplus(p_i)) - <p_i,t_j>/HW ]
//      (pairs with all-zero target j are skipped -> loss entry 0)
#define NB 8
#define NP 8
#define NT 16
#define HW (512 * 512)
#define HW4 (HW / 4)               // 65536 float4 per image
#define NACC (NP + NP * NT + NT)   // 152 accumulators per batch
#define THREADS 256
#define BLOCKS_PER_B 256           // 256 blocks * 256 threads = HW4 exactly
#define NROW 32                    // 4 waves * 8 eight-lane groups
#define LDSPITCH 153               // 153 % 32 = 25 -> conflict-free column reads

__device__ __forceinline__ float softplus1(float x) {
  // stable: max(x,0) + log(1 + exp(-|x|)); hw exp2/log2-based, err ~1e-6.
  return fmaxf(x, 0.0f) + __logf(1.0f + __expf(-fabsf(x)));
}

// Stage 1: one float4 pixel-slice per thread. Compute each partial sum and
// immediately 8-lane-reduce it (3 DPP shuffles), stash in LDS, fold, atomic.
__global__ __launch_bounds__(THREADS, 4) void sam_partial(
    const float* __restrict__ pred, const float* __restrict__ targ,
    float* __restrict__ ws) {
  const int b   = blockIdx.x >> 8;           // blockIdx.x = b*256 + blk
  const int blk = blockIdx.x & 255;
  const int tid = threadIdx.x;
  const int idx = (blk << 8) | tid;          // float4 index within image
  const int lane = tid & 63;
  const int wid  = tid >> 6;
  const int row  = (wid << 3) | (lane >> 3); // 0..31
  const bool wr  = (lane & 7) == 0;

  __shared__ float red[NROW][LDSPITCH];

  const float4* __restrict__ pb =
      reinterpret_cast<const float4*>(pred) + (size_t)b * NP * HW4;
  const float4* __restrict__ tb =
      reinterpret_cast<const float4*>(targ) + (size_t)b * NT * HW4;

  // Issue all 24 loads up-front for maximal MLP.
  float4 p[NP];
#pragma unroll
  for (int i = 0; i < NP; ++i) p[i] = pb[(size_t)i * HW4 + idx];
  float4 t[NT];
#pragma unroll
  for (int j = 0; j < NT; ++j) t[j] = tb[(size_t)j * HW4 + idx];

  // reduce-within-8-lanes + stash (offsets 4,2,1 stay inside a DPP row)
#define STASH(a, expr)                                   \
  {                                                      \
    float v_ = (expr);                                   \
    v_ += __shfl_down(v_, 4);                            \
    v_ += __shfl_down(v_, 2);                            \
    v_ += __shfl_down(v_, 1);                            \
    if (wr) red[row][(a)] = v_;                          \
  }

#pragma unroll
  for (int i = 0; i < NP; ++i) {
    STASH(i, (softplus1(p[i].x) + softplus1(p[i].y)) +
             (softplus1(p[i].z) + softplus1(p[i].w)));
  }
#pragma unroll
  for (int i = 0; i < NP; ++i) {
#pragma unroll
    for (int j = 0; j < NT; ++j) {
      STASH(NP + i * NT + j,
            fmaf(p[i].x, t[j].x,
            fmaf(p[i].y, t[j].y,
            fmaf(p[i].z, t[j].z, p[i].w * t[j].w))));
    }
  }
#pragma unroll
  for (int j = 0; j < NT; ++j) {
    STASH(NP + NP * NT + j, (t[j].x + t[j].y) + (t[j].z + t[j].w));
  }
#undef STASH

  __syncthreads();
  if (tid < NACC) {
    float v = 0.0f;
#pragma unroll
    for (int r = 0; r < NROW; ++r) v += red[r][tid];
    atomicAdd(ws + (size_t)b * NACC + tid, v);
  }
}

// Stage 2: one wave; thread t owns (b = t>>3, i = t&7).
__global__ void sam_final(const float* __restrict__ ws,
                          float* __restrict__ out) {
  const int t = threadIdx.x;  // 64 threads
  const int b = t >> 3;
  const int i = t & 7;
  const float* w = ws + (size_t)b * NACC;
  const float spsum = w[i];
  float m = 3.4e38f;
#pragma unroll
  for (int j = 0; j < NT; ++j) {
    const float tsj = w[NP + NP * NT + j];
    const float v =
        (tsj == 0.0f) ? 0.0f : (spsum - w[NP + i * NT + j]) * (1.0f / HW);
    m = fminf(m, v);
  }
  float s = m;
#pragma unroll
  for (int off = 32; off > 0; off >>= 1) s += __shfl_down(s, off);
  if (t == 0) out[0] = 5.0f * s * (1.0f / 64.0f);
}

extern "C" void kernel_launch(void* const* d_in, const int* in_sizes, int n_in,
                              void* d_out, int out_size, void* d_ws,
                              size_t ws_size, hipStream_t stream) {
  const float* pred = (const float*)d_in[0];
  const float* targ = (const float*)d_in[1];
  float* out = (float*)d_out;
  float* ws = (float*)d_ws;

  hipMemsetAsync(ws, 0, (size_t)NB * NACC * sizeof(float), stream);
  sam_partial<<<dim3(NB * BLOCKS_PER_B), THREADS, 0, stream>>>(pred, targ, ws);
  sam_final<<<1, 64, 0, stream>>>(ws, out);
}